// Round 1
// baseline (400.868 us; speedup 1.0000x reference)
//
#include <hip/hip_runtime.h>
#include <math.h>

#define NN 50000
#define NE 600000
#define HD 128
#define NL 3

// ---------------- degree / normalization ----------------

__global__ void count_deg_k(const int* __restrict__ dst, int* __restrict__ deg) {
    int e = blockIdx.x * blockDim.x + threadIdx.x;
    if (e < NE) atomicAdd(&deg[dst[e]], 1);
}

__global__ void inv_sqrt_k(const int* __restrict__ deg, float* __restrict__ isq) {
    int v = blockIdx.x * blockDim.x + threadIdx.x;
    if (v < NN) isq[v] = 1.0f / sqrtf((float)(deg[v] + 1)); // +1 = self loop; always > 0
}

// single-block exclusive scan of deg -> rowptr (50001 entries)
__global__ __launch_bounds__(1024) void scan_k(const int* __restrict__ deg,
                                               int* __restrict__ rowptr) {
    __shared__ int wsum[16];
    __shared__ int carry_s;
    int tid = threadIdx.x;
    int lane = tid & 63, w = tid >> 6;
    if (tid == 0) carry_s = 0;
    __syncthreads();
    for (int base = 0; base < NN; base += 1024) {
        int v = base + tid;
        int x = (v < NN) ? deg[v] : 0;
        int s = x;
        #pragma unroll
        for (int off = 1; off < 64; off <<= 1) {
            int t = __shfl_up(s, off);
            if (lane >= off) s += t;
        }
        if (lane == 63) wsum[w] = s;
        __syncthreads();
        if (w == 0) {
            int t = (lane < 16) ? wsum[lane] : 0;
            #pragma unroll
            for (int off = 1; off < 16; off <<= 1) {
                int u = __shfl_up(t, off);
                if (lane >= off) t += u;
            }
            if (lane < 16) wsum[lane] = t;
        }
        __syncthreads();
        int c = carry_s;
        int incl = s + ((w > 0) ? wsum[w - 1] : 0);
        if (v < NN) rowptr[v] = c + incl - x; // exclusive
        __syncthreads();
        if (tid == 1023) carry_s = c + incl;
        __syncthreads();
    }
    if (tid == 0) rowptr[NN] = carry_s;
}

__global__ void csr_fill_k(const int* __restrict__ src, const int* __restrict__ dst,
                           const int* __restrict__ rowptr, int* __restrict__ cursor,
                           int* __restrict__ csr) {
    int e = blockIdx.x * blockDim.x + threadIdx.x;
    if (e < NE) {
        int d = dst[e];
        int pos = atomicAdd(&cursor[d], 1);
        csr[rowptr[d] + pos] = src[e];
    }
}

// ---------------- GEMM: out = A[nrows,128] @ W[128,128]; epilogue per MODE ----------------
// MODE 0: out[r][c] = acc + bias[c]          (input transform)
// MODE 1: out[r][c] = acc * rowscale[r]      (pre-scaled messages mh)
template<int MODE>
__global__ __launch_bounds__(256) void gemm128_k(const float* __restrict__ A,
                                                 const float* __restrict__ W,
                                                 const float* __restrict__ bs,
                                                 float* __restrict__ out, int nrows) {
    __shared__ float sh[64][20];   // 64 rows x 16 k (padded to 20 for 16B-aligned f4 writes)
    __shared__ float sw[16][128];  // 16 k x 128 cols
    int tid = threadIdx.x;
    int tr = tid >> 5, tc = tid & 31; // 8 thread-rows x 32 thread-cols
    int r0 = blockIdx.x * 64;
    float4 acc[8];
    #pragma unroll
    for (int i = 0; i < 8; ++i) acc[i] = make_float4(0.f, 0.f, 0.f, 0.f);

    for (int kc = 0; kc < HD; kc += 16) {
        // stage W[kc..kc+15][0..127] (coalesced float4)
        #pragma unroll
        for (int q = 0; q < 2; ++q) {
            int f = tid + q * 256;           // 0..511 float4s
            int k = f >> 5, c4 = (f & 31) * 4;
            *(float4*)&sw[k][c4] = *(const float4*)&W[(kc + k) * HD + c4];
        }
        // stage A[r0..r0+63][kc..kc+15]
        {
            int r = tid >> 2, kq = (tid & 3) * 4;
            int gr = r0 + r;
            float4 a = make_float4(0.f, 0.f, 0.f, 0.f);
            if (gr < nrows) a = *(const float4*)&A[(size_t)gr * HD + kc + kq];
            *(float4*)&sh[r][kq] = a;
        }
        __syncthreads();
        #pragma unroll
        for (int kk = 0; kk < 16; ++kk) {
            float4 b = *(const float4*)&sw[kk][tc * 4];
            #pragma unroll
            for (int i = 0; i < 8; ++i) {
                float a = sh[tr * 8 + i][kk];
                acc[i].x += a * b.x; acc[i].y += a * b.y;
                acc[i].z += a * b.z; acc[i].w += a * b.w;
            }
        }
        __syncthreads();
    }

    if (MODE == 0) {
        float4 b4 = *(const float4*)&bs[tc * 4];
        #pragma unroll
        for (int i = 0; i < 8; ++i) {
            int r = r0 + tr * 8 + i;
            if (r < nrows) {
                float4 o = acc[i];
                o.x += b4.x; o.y += b4.y; o.z += b4.z; o.w += b4.w;
                *(float4*)&out[(size_t)r * HD + tc * 4] = o;
            }
        }
    } else {
        #pragma unroll
        for (int i = 0; i < 8; ++i) {
            int r = r0 + tr * 8 + i;
            if (r < nrows) {
                float s = bs[r];
                float4 o = acc[i];
                o.x *= s; o.y *= s; o.z *= s; o.w *= s;
                *(float4*)&out[(size_t)r * HD + tc * 4] = o;
            }
        }
    }
}

// ---------------- aggregation: one wave per node ----------------
// h[v] = gelu( isq[v]*(sum_in mh[src] + mh[v]) + b ) + h[v]
__global__ __launch_bounds__(256) void aggregate_k(const float* __restrict__ mh,
                                                   const int* __restrict__ rowptr,
                                                   const int* __restrict__ csr,
                                                   const float* __restrict__ isq,
                                                   const float* __restrict__ bias,
                                                   float* __restrict__ h) {
    int gw = (int)((blockIdx.x * blockDim.x + threadIdx.x) >> 6);
    int lane = threadIdx.x & 63;
    if (gw >= NN) return;
    int v = gw;
    int beg = rowptr[v], end = rowptr[v + 1];
    float2 acc = *(const float2*)&mh[(size_t)v * HD + lane * 2]; // self-loop term
    for (int i = beg; i < end; i += 64) {
        int mye = (i + lane < end) ? csr[i + lane] : 0;
        int cnt = min(64, end - i);
        for (int j = 0; j < cnt; ++j) {
            int s = __shfl(mye, j);
            float2 t = *(const float2*)&mh[(size_t)s * HD + lane * 2];
            acc.x += t.x; acc.y += t.y;
        }
    }
    float is = isq[v];
    float2 b = *(const float2*)&bias[lane * 2];
    float ax = acc.x * is + b.x;
    float ay = acc.y * is + b.y;
    float gx = 0.5f * ax * (1.f + erff(ax * 0.70710678118654752f));
    float gy = 0.5f * ay * (1.f + erff(ay * 0.70710678118654752f));
    float2 hv = *(const float2*)&h[(size_t)v * HD + lane * 2];
    hv.x += gx; hv.y += gy;
    *(float2*)&h[(size_t)v * HD + lane * 2] = hv;
}

// ---------------- launch ----------------

static inline size_t align_up(size_t x, size_t a) { return (x + a - 1) & ~(a - 1); }

extern "C" void kernel_launch(void* const* d_in, const int* in_sizes, int n_in,
                              void* d_out, int out_size, void* d_ws, size_t ws_size,
                              hipStream_t stream) {
    const float* x        = (const float*)d_in[0];
    const int*   eidx     = (const int*)d_in[1];
    const float* W_in     = (const float*)d_in[2];
    const float* b_in     = (const float*)d_in[3];
    const float* W_layers = (const float*)d_in[4];
    const float* b_layers = (const float*)d_in[5];
    float* h = (float*)d_out;

    const int* src = eidx;          // edge_index[0]
    const int* dst = eidx + NE;     // edge_index[1]

    // workspace carve-up (~29 MB)
    char* p = (char*)d_ws;
    float* mh = (float*)p;        p += align_up(sizeof(float) * (size_t)NN * HD, 256);
    float* isq = (float*)p;       p += align_up(sizeof(float) * NN, 256);
    int* deg = (int*)p;           p += align_up(sizeof(int) * NN, 256);
    int* rowptr = (int*)p;        p += align_up(sizeof(int) * (NN + 1), 256);
    int* cursor = (int*)p;        p += align_up(sizeof(int) * NN, 256);
    int* csr = (int*)p;           p += align_up(sizeof(int) * NE, 256);

    hipMemsetAsync(deg, 0, sizeof(int) * NN, stream);
    hipMemsetAsync(cursor, 0, sizeof(int) * NN, stream);

    count_deg_k<<<(NE + 255) / 256, 256, 0, stream>>>(dst, deg);
    inv_sqrt_k<<<(NN + 255) / 256, 256, 0, stream>>>(deg, isq);
    scan_k<<<1, 1024, 0, stream>>>(deg, rowptr);
    csr_fill_k<<<(NE + 255) / 256, 256, 0, stream>>>(src, dst, rowptr, cursor, csr);

    int gblocks = (NN + 63) / 64;
    // h = x @ W_in + b_in
    gemm128_k<0><<<gblocks, 256, 0, stream>>>(x, W_in, b_in, h, NN);

    for (int l = 0; l < NL; ++l) {
        // mh = (h @ W_l) * isq[row]
        gemm128_k<1><<<gblocks, 256, 0, stream>>>(h, W_layers + (size_t)l * HD * HD, isq, mh, NN);
        // h = gelu(isq*(sum mh[src] + mh[v]) + b_l) + h
        aggregate_k<<<(NN + 3) / 4, 256, 0, stream>>>(mh, rowptr, csr, isq,
                                                      b_layers + (size_t)l * HD, h);
    }
}

// Round 2
// 314.316 us; speedup vs baseline: 1.2754x; 1.2754x over previous
//
#include <hip/hip_runtime.h>
#include <hip/hip_bf16.h>
#include <math.h>

#define NN 50000
#define NE 600000
#define HD 128
#define NL 3

typedef __attribute__((ext_vector_type(8))) short short8;
typedef __attribute__((ext_vector_type(4))) float f32x4;

__device__ __forceinline__ ushort f2bf(float v) {
    union { float f; unsigned u; } c; c.f = v;
    unsigned u = c.u;
    u = (u + 0x7fffu + ((u >> 16) & 1u)) >> 16;
    return (ushort)u;
}
__device__ __forceinline__ float bf2f(ushort b) {
    union { unsigned u; float f; } c; c.u = ((unsigned)b) << 16;
    return c.f;
}

// ---------------- degree / normalization ----------------

__global__ void count_deg_k(const int* __restrict__ dst, int* __restrict__ deg) {
    int e = blockIdx.x * blockDim.x + threadIdx.x;
    if (e < NE) atomicAdd(&deg[dst[e]], 1);
}

__global__ void inv_sqrt_k(const int* __restrict__ deg, float* __restrict__ isq) {
    int v = blockIdx.x * blockDim.x + threadIdx.x;
    if (v < NN) isq[v] = 1.0f / sqrtf((float)(deg[v] + 1)); // +1 self loop
}

// single-block exclusive scan of deg -> rowptr
__global__ __launch_bounds__(1024) void scan_k(const int* __restrict__ deg,
                                               int* __restrict__ rowptr) {
    __shared__ int wsum[16];
    __shared__ int carry_s;
    int tid = threadIdx.x;
    int lane = tid & 63, w = tid >> 6;
    if (tid == 0) carry_s = 0;
    __syncthreads();
    for (int base = 0; base < NN; base += 1024) {
        int v = base + tid;
        int x = (v < NN) ? deg[v] : 0;
        int s = x;
        #pragma unroll
        for (int off = 1; off < 64; off <<= 1) {
            int t = __shfl_up(s, off);
            if (lane >= off) s += t;
        }
        if (lane == 63) wsum[w] = s;
        __syncthreads();
        if (w == 0) {
            int t = (lane < 16) ? wsum[lane] : 0;
            #pragma unroll
            for (int off = 1; off < 16; off <<= 1) {
                int u = __shfl_up(t, off);
                if (lane >= off) t += u;
            }
            if (lane < 16) wsum[lane] = t;
        }
        __syncthreads();
        int c = carry_s;
        int incl = s + ((w > 0) ? wsum[w - 1] : 0);
        if (v < NN) rowptr[v] = c + incl - x;
        __syncthreads();
        if (tid == 1023) carry_s = c + incl;
        __syncthreads();
    }
    if (tid == 0) rowptr[NN] = carry_s;
}

__global__ void csr_fill_k(const int* __restrict__ src, const int* __restrict__ dst,
                           const int* __restrict__ rowptr, int* __restrict__ cursor,
                           int* __restrict__ csr) {
    int e = blockIdx.x * blockDim.x + threadIdx.x;
    if (e < NE) {
        int d = dst[e];
        int pos = atomicAdd(&cursor[d], 1);
        csr[rowptr[d] + pos] = src[e];
    }
}

// ---------------- weight transpose+convert: WT[m][c][k] = bf16(W_m[k][c]) ----
__global__ void transpose_w_k(const float* __restrict__ W_in,
                              const float* __restrict__ W_layers,
                              ushort* __restrict__ WT) {
    int idx = blockIdx.x * blockDim.x + threadIdx.x; // 4*128*128
    int m = idx >> 14;
    int c = (idx >> 7) & 127;
    int k = idx & 127;
    const float* W = (m == 0) ? W_in : (W_layers + (size_t)(m - 1) * HD * HD);
    WT[idx] = f2bf(W[k * HD + c]);
}

// ---------------- MFMA GEMM: out = A[nrows,128] @ W[128,128] -----------------
// MODE 0: A is f32 (x). out_f32 = acc + bias[col]; out_bf16 = bf16(same)
// MODE 1: A is bf16 (hb). out_bf16 = bf16(acc * isq[row])
template<int MODE>
__global__ __launch_bounds__(256) void gemm_mfma_k(const void* __restrict__ Av,
                                                   const ushort* __restrict__ WT,
                                                   const float* __restrict__ bs,
                                                   float* __restrict__ out_f32,
                                                   ushort* __restrict__ out_bf16,
                                                   int nrows) {
    __shared__ ushort swT[HD * HD]; // 32 KB, XOR-swizzled [col][k]
    int tid = threadIdx.x;
    #pragma unroll
    for (int i = 0; i < 8; ++i) {
        int chunk = tid + i * 256;      // 16B chunks, 2048 total
        int lin = chunk << 4;           // linear byte addr
        int n = lin >> 8;               // row (col-of-W)
        int swz = lin ^ ((n & 7) << 4);
        *(float4*)((char*)swT + swz) = *(const float4*)(WT + chunk * 8);
    }
    __syncthreads();

    int w = tid >> 6, l = tid & 63;
    int ar = l & 15, ag = l >> 4;       // operand row/col = ar, k-group = ag
    int r0 = blockIdx.x * 64 + w * 16;
    int arow = r0 + ar;
    bool arow_ok = arow < nrows;

    short8 afr[4];
    #pragma unroll
    for (int ks = 0; ks < 4; ++ks) {
        if (MODE == 0) {
            short8 fr = {0,0,0,0,0,0,0,0};
            if (arow_ok) {
                const float* Af = (const float*)Av;
                float4 p0 = *(const float4*)(Af + (size_t)arow * HD + ks * 32 + ag * 8);
                float4 p1 = *(const float4*)(Af + (size_t)arow * HD + ks * 32 + ag * 8 + 4);
                fr[0] = (short)f2bf(p0.x); fr[1] = (short)f2bf(p0.y);
                fr[2] = (short)f2bf(p0.z); fr[3] = (short)f2bf(p0.w);
                fr[4] = (short)f2bf(p1.x); fr[5] = (short)f2bf(p1.y);
                fr[6] = (short)f2bf(p1.z); fr[7] = (short)f2bf(p1.w);
            }
            afr[ks] = fr;
        } else {
            const ushort* Ab = (const ushort*)Av;
            afr[ks] = arow_ok ? *(const short8*)(Ab + (size_t)arow * HD + ks * 32 + ag * 8)
                              : short8{0,0,0,0,0,0,0,0};
        }
    }

    f32x4 acc[8];
    #pragma unroll
    for (int t = 0; t < 8; ++t) acc[t] = f32x4{0.f, 0.f, 0.f, 0.f};

    #pragma unroll
    for (int ks = 0; ks < 4; ++ks) {
        #pragma unroll
        for (int t = 0; t < 8; ++t) {
            int n = t * 16 + ar;
            int lin = (n << 8) + ks * 64 + ag * 16;
            int swz = lin ^ ((ar & 7) << 4);
            short8 b = *(const short8*)((const char*)swT + swz);
            acc[t] = __builtin_amdgcn_mfma_f32_16x16x32_bf16(afr[ks], b, acc[t], 0, 0, 0);
        }
    }

    // epilogue: D mapping col = lane&15 (=ar), row = ag*4 + q
    #pragma unroll
    for (int q = 0; q < 4; ++q) {
        int row = r0 + ag * 4 + q;
        if (row >= nrows) continue;
        if (MODE == 0) {
            #pragma unroll
            for (int t = 0; t < 8; ++t) {
                int col = t * 16 + ar;
                float v = acc[t][q] + bs[col];
                out_f32[(size_t)row * HD + col] = v;
                out_bf16[(size_t)row * HD + col] = f2bf(v);
            }
        } else {
            float s = bs[row];
            #pragma unroll
            for (int t = 0; t < 8; ++t) {
                int col = t * 16 + ar;
                out_bf16[(size_t)row * HD + col] = f2bf(acc[t][q] * s);
            }
        }
    }
}

// ---------------- aggregation: one wave per node ----------------
// h[v] = gelu( isq[v]*(sum_in mh[src] + mh[v]) + b ) + h[v];  hb = bf16(h)
__global__ __launch_bounds__(256) void aggregate_k(const ushort* __restrict__ mh,
                                                   const int* __restrict__ rowptr,
                                                   const int* __restrict__ csr,
                                                   const float* __restrict__ isq,
                                                   const float* __restrict__ bias,
                                                   float* __restrict__ h,
                                                   ushort* __restrict__ hb) {
    int gw = (int)((blockIdx.x * blockDim.x + threadIdx.x) >> 6);
    int lane = threadIdx.x & 63;
    if (gw >= NN) return;
    int v = gw;
    int beg = rowptr[v], end = rowptr[v + 1];
    ushort2 mself = *(const ushort2*)&mh[(size_t)v * HD + lane * 2];
    float accx = bf2f(mself.x), accy = bf2f(mself.y);
    for (int i = beg; i < end; i += 64) {
        int mye = (i + lane < end) ? csr[i + lane] : 0;
        int cnt = min(64, end - i);
        for (int j = 0; j < cnt; ++j) {
            int s = __shfl(mye, j);
            ushort2 t = *(const ushort2*)&mh[(size_t)s * HD + lane * 2];
            accx += bf2f(t.x); accy += bf2f(t.y);
        }
    }
    float is = isq[v];
    float2 b = *(const float2*)&bias[lane * 2];
    float ax = accx * is + b.x;
    float ay = accy * is + b.y;
    float gx = 0.5f * ax * (1.f + erff(ax * 0.70710678118654752f));
    float gy = 0.5f * ay * (1.f + erff(ay * 0.70710678118654752f));
    float2 hv = *(const float2*)&h[(size_t)v * HD + lane * 2];
    hv.x += gx; hv.y += gy;
    *(float2*)&h[(size_t)v * HD + lane * 2] = hv;
    ushort2 hbv; hbv.x = f2bf(hv.x); hbv.y = f2bf(hv.y);
    *(ushort2*)&hb[(size_t)v * HD + lane * 2] = hbv;
}

// ---------------- launch ----------------

static inline size_t align_up(size_t x, size_t a) { return (x + a - 1) & ~(a - 1); }

extern "C" void kernel_launch(void* const* d_in, const int* in_sizes, int n_in,
                              void* d_out, int out_size, void* d_ws, size_t ws_size,
                              hipStream_t stream) {
    const float* x        = (const float*)d_in[0];
    const int*   eidx     = (const int*)d_in[1];
    const float* W_in     = (const float*)d_in[2];
    const float* b_in     = (const float*)d_in[3];
    const float* W_layers = (const float*)d_in[4];
    const float* b_layers = (const float*)d_in[5];
    float* h = (float*)d_out;

    const int* src = eidx;
    const int* dst = eidx + NE;

    // workspace carve-up (~32 MB)
    char* p = (char*)d_ws;
    ushort* mh = (ushort*)p;      p += align_up(sizeof(ushort) * (size_t)NN * HD, 256);
    ushort* hb = (ushort*)p;      p += align_up(sizeof(ushort) * (size_t)NN * HD, 256);
    ushort* WT = (ushort*)p;      p += align_up(sizeof(ushort) * 4 * HD * HD, 256);
    float* isq = (float*)p;       p += align_up(sizeof(float) * NN, 256);
    int* deg = (int*)p;           p += align_up(sizeof(int) * NN, 256);
    int* rowptr = (int*)p;        p += align_up(sizeof(int) * (NN + 1), 256);
    int* cursor = (int*)p;        p += align_up(sizeof(int) * NN, 256);
    int* csr = (int*)p;           p += align_up(sizeof(int) * NE, 256);

    hipMemsetAsync(deg, 0, sizeof(int) * NN, stream);
    hipMemsetAsync(cursor, 0, sizeof(int) * NN, stream);

    transpose_w_k<<<(4 * HD * HD) / 256, 256, 0, stream>>>(W_in, W_layers, WT);
    count_deg_k<<<(NE + 255) / 256, 256, 0, stream>>>(dst, deg);
    inv_sqrt_k<<<(NN + 255) / 256, 256, 0, stream>>>(deg, isq);
    scan_k<<<1, 1024, 0, stream>>>(deg, rowptr);
    csr_fill_k<<<(NE + 255) / 256, 256, 0, stream>>>(src, dst, rowptr, cursor, csr);

    int gblocks = (NN + 63) / 64; // 782
    // h = x @ W_in + b_in  (also hb = bf16(h))
    gemm_mfma_k<0><<<gblocks, 256, 0, stream>>>(x, WT, b_in, h, hb, NN);

    for (int l = 0; l < NL; ++l) {
        // mh = bf16((hb @ W_l) * isq[row])
        gemm_mfma_k<1><<<gblocks, 256, 0, stream>>>(hb, WT + (size_t)(l + 1) * HD * HD,
                                                    isq, nullptr, mh, NN);
        // h = gelu(isq*(sum mh[src] + mh[v]) + b_l) + h ; hb = bf16(h)
        aggregate_k<<<(NN + 3) / 4, 256, 0, stream>>>(mh, rowptr, csr, isq,
                                                      b_layers + (size_t)l * HD, h, hb);
    }
}

// Round 3
// 291.903 us; speedup vs baseline: 1.3733x; 1.0768x over previous
//
#include <hip/hip_runtime.h>
#include <hip/hip_bf16.h>
#include <math.h>

#define NN 50000
#define NE 600000
#define HD 128
#define NL 3
#define NBLK 49   // ceil(NN/1024)

typedef __attribute__((ext_vector_type(8))) short short8;
typedef __attribute__((ext_vector_type(4))) float f32x4;

__device__ __forceinline__ ushort f2bf(float v) {
    union { float f; unsigned u; } c; c.f = v;
    unsigned u = c.u;
    u = (u + 0x7fffu + ((u >> 16) & 1u)) >> 16;
    return (ushort)u;
}
__device__ __forceinline__ float bf2f(ushort b) {
    union { unsigned u; float f; } c; c.u = ((unsigned)b) << 16;
    return c.f;
}

// ---------------- degree ----------------

__global__ void count_deg_k(const int* __restrict__ dst, int* __restrict__ deg) {
    int e = blockIdx.x * blockDim.x + threadIdx.x;
    if (e < NE) atomicAdd(&deg[dst[e]], 1);
}

// ---------------- 3-phase scan: deg -> rowptr (exclusive) ----------------

__global__ __launch_bounds__(1024) void scan_partial_k(const int* __restrict__ deg,
                                                       int* __restrict__ rowptr,
                                                       int* __restrict__ partial) {
    __shared__ int wsum[16];
    int tid = threadIdx.x;
    int lane = tid & 63, w = tid >> 6;
    int v = blockIdx.x * 1024 + tid;
    int x = (v < NN) ? deg[v] : 0;
    int s = x;
    #pragma unroll
    for (int off = 1; off < 64; off <<= 1) {
        int t = __shfl_up(s, off);
        if (lane >= off) s += t;
    }
    if (lane == 63) wsum[w] = s;
    __syncthreads();
    if (w == 0) {
        int t = (lane < 16) ? wsum[lane] : 0;
        #pragma unroll
        for (int off = 1; off < 16; off <<= 1) {
            int u = __shfl_up(t, off);
            if (lane >= off) t += u;
        }
        if (lane < 16) wsum[lane] = t;
    }
    __syncthreads();
    int incl = s + ((w > 0) ? wsum[w - 1] : 0);
    if (v < NN) rowptr[v] = incl - x;        // block-local exclusive
    if (tid == 1023) partial[blockIdx.x] = incl; // block total
}

__global__ void scan_partials2_k(int* __restrict__ partial) {
    int lane = threadIdx.x & 63;
    int x = (lane < NBLK) ? partial[lane] : 0;
    int s = x;
    #pragma unroll
    for (int off = 1; off < 64; off <<= 1) {
        int t = __shfl_up(s, off);
        if (lane >= off) s += t;
    }
    if (lane < NBLK) partial[lane] = s - x;  // exclusive
    if (lane == NBLK - 1) partial[NBLK] = s; // grand total
}

__global__ __launch_bounds__(1024) void add_off_isq_k(const int* __restrict__ deg,
                                                      int* __restrict__ rowptr,
                                                      const int* __restrict__ partial,
                                                      float* __restrict__ isq) {
    int v = blockIdx.x * 1024 + threadIdx.x;
    if (v < NN) {
        rowptr[v] += partial[blockIdx.x];
        isq[v] = rsqrtf((float)(deg[v] + 1)); // +1 self loop
    }
    if (v == 0) rowptr[NN] = partial[NBLK];
}

__global__ void csr_fill_k(const int* __restrict__ src, const int* __restrict__ dst,
                           const int* __restrict__ rowptr, int* __restrict__ cursor,
                           int* __restrict__ csr) {
    int e = blockIdx.x * blockDim.x + threadIdx.x;
    if (e < NE) {
        int d = dst[e];
        int pos = atomicAdd(&cursor[d], 1);
        csr[rowptr[d] + pos] = src[e];
    }
}

// ---------------- weight transpose+convert: WT[m][c][k] = bf16(W_m[k][c]) ----
__global__ void transpose_w_k(const float* __restrict__ W_in,
                              const float* __restrict__ W_layers,
                              ushort* __restrict__ WT) {
    int idx = blockIdx.x * blockDim.x + threadIdx.x; // 4*128*128
    int m = idx >> 14;
    int c = (idx >> 7) & 127;
    int k = idx & 127;
    const float* W = (m == 0) ? W_in : (W_layers + (size_t)(m - 1) * HD * HD);
    WT[idx] = f2bf(W[k * HD + c]);
}

// ---------------- MFMA GEMM: out = A[nrows,128](f32) @ W[128,128] ------------
// MODE 0: out_f32[r][c] = acc + bias[c]
// MODE 1: out_b16[r][c] = bf16(acc * isq[r])
template<int MODE>
__global__ __launch_bounds__(256) void gemm_mfma_k(const float* __restrict__ A,
                                                   const ushort* __restrict__ WT,
                                                   const float* __restrict__ bs,
                                                   float* __restrict__ out_f32,
                                                   ushort* __restrict__ out_b16,
                                                   int nrows) {
    __shared__ ushort swT[HD * HD]; // 32 KB, XOR-swizzled [col][k]
    int tid = threadIdx.x;
    #pragma unroll
    for (int i = 0; i < 8; ++i) {
        int chunk = tid + i * 256;      // 16B chunks, 2048 total
        int lin = chunk << 4;
        int n = lin >> 8;
        int swz = lin ^ ((n & 7) << 4);
        *(float4*)((char*)swT + swz) = *(const float4*)(WT + chunk * 8);
    }
    __syncthreads();

    int w = tid >> 6, l = tid & 63;
    int ar = l & 15, ag = l >> 4;
    int r0 = blockIdx.x * 64 + w * 16;
    int arow = r0 + ar;
    bool arow_ok = arow < nrows;

    short8 afr[4];
    #pragma unroll
    for (int ks = 0; ks < 4; ++ks) {
        short8 fr = {0,0,0,0,0,0,0,0};
        if (arow_ok) {
            float4 p0 = *(const float4*)(A + (size_t)arow * HD + ks * 32 + ag * 8);
            float4 p1 = *(const float4*)(A + (size_t)arow * HD + ks * 32 + ag * 8 + 4);
            fr[0] = (short)f2bf(p0.x); fr[1] = (short)f2bf(p0.y);
            fr[2] = (short)f2bf(p0.z); fr[3] = (short)f2bf(p0.w);
            fr[4] = (short)f2bf(p1.x); fr[5] = (short)f2bf(p1.y);
            fr[6] = (short)f2bf(p1.z); fr[7] = (short)f2bf(p1.w);
        }
        afr[ks] = fr;
    }

    f32x4 acc[8];
    #pragma unroll
    for (int t = 0; t < 8; ++t) acc[t] = f32x4{0.f, 0.f, 0.f, 0.f};

    #pragma unroll
    for (int ks = 0; ks < 4; ++ks) {
        #pragma unroll
        for (int t = 0; t < 8; ++t) {
            int n = t * 16 + ar;
            int lin = (n << 8) + ks * 64 + ag * 16;
            int swz = lin ^ ((ar & 7) << 4);
            short8 b = *(const short8*)((const char*)swT + swz);
            acc[t] = __builtin_amdgcn_mfma_f32_16x16x32_bf16(afr[ks], b, acc[t], 0, 0, 0);
        }
    }

    #pragma unroll
    for (int q = 0; q < 4; ++q) {
        int row = r0 + ag * 4 + q;
        if (row >= nrows) continue;
        if (MODE == 0) {
            #pragma unroll
            for (int t = 0; t < 8; ++t) {
                int col = t * 16 + ar;
                out_f32[(size_t)row * HD + col] = acc[t][q] + bs[col];
            }
        } else {
            float s = bs[row];
            #pragma unroll
            for (int t = 0; t < 8; ++t) {
                int col = t * 16 + ar;
                out_b16[(size_t)row * HD + col] = f2bf(acc[t][q] * s);
            }
        }
    }
}

// ---------------- aggregation: one wave per node, 8-wide batched gather ------
// h[v] = gelu( isq[v]*(sum_in mh[src] + mh[v]) + b ) + h[v]
__global__ __launch_bounds__(256) void aggregate_k(const ushort* __restrict__ mh,
                                                   const int* __restrict__ rowptr,
                                                   const int* __restrict__ csr,
                                                   const float* __restrict__ isq,
                                                   const float* __restrict__ bias,
                                                   float* __restrict__ h) {
    int gw = (int)((blockIdx.x * blockDim.x + threadIdx.x) >> 6);
    int lane = threadIdx.x & 63;
    if (gw >= NN) return;
    int v = gw;
    int beg = rowptr[v], end = rowptr[v + 1];
    ushort2 ms = *(const ushort2*)&mh[(size_t)v * HD + lane * 2]; // self loop
    float accx = bf2f(ms.x), accy = bf2f(ms.y);

    for (int i = beg; i < end; i += 64) {
        int cnt = min(64, end - i);
        int mye = (i + lane < end) ? csr[i + lane] : 0;
        for (int j = 0; j < cnt; j += 8) {
            float tx[8], ty[8];
            #pragma unroll
            for (int u = 0; u < 8; ++u) {
                int jj = j + u;
                bool ok = jj < cnt;          // wave-uniform
                int s = __shfl(mye, ok ? jj : 0);
                ushort2 t = *(const ushort2*)&mh[(size_t)s * HD + lane * 2];
                tx[u] = ok ? bf2f(t.x) : 0.f;
                ty[u] = ok ? bf2f(t.y) : 0.f;
            }
            #pragma unroll
            for (int u = 0; u < 8; ++u) { accx += tx[u]; accy += ty[u]; }
        }
    }

    float is = isq[v];
    float2 b = *(const float2*)&bias[lane * 2];
    float ax = accx * is + b.x;
    float ay = accy * is + b.y;
    float gx = 0.5f * ax * (1.f + erff(ax * 0.70710678118654752f));
    float gy = 0.5f * ay * (1.f + erff(ay * 0.70710678118654752f));
    float2 hv = *(const float2*)&h[(size_t)v * HD + lane * 2];
    hv.x += gx; hv.y += gy;
    *(float2*)&h[(size_t)v * HD + lane * 2] = hv;
}

// ---------------- launch ----------------

static inline size_t align_up(size_t x, size_t a) { return (x + a - 1) & ~(a - 1); }

extern "C" void kernel_launch(void* const* d_in, const int* in_sizes, int n_in,
                              void* d_out, int out_size, void* d_ws, size_t ws_size,
                              hipStream_t stream) {
    const float* x        = (const float*)d_in[0];
    const int*   eidx     = (const int*)d_in[1];
    const float* W_in     = (const float*)d_in[2];
    const float* b_in     = (const float*)d_in[3];
    const float* W_layers = (const float*)d_in[4];
    const float* b_layers = (const float*)d_in[5];
    float* h = (float*)d_out;

    const int* src = eidx;
    const int* dst = eidx + NE;

    // workspace carve-up (~20 MB)
    char* p = (char*)d_ws;
    ushort* mh = (ushort*)p;      p += align_up(sizeof(ushort) * (size_t)NN * HD, 256);
    ushort* WT = (ushort*)p;      p += align_up(sizeof(ushort) * 4 * HD * HD, 256);
    float* isq = (float*)p;       p += align_up(sizeof(float) * NN, 256);
    int* deg = (int*)p;           // deg and cursor adjacent -> one memset
    int* cursor = deg + NN;       p += align_up(sizeof(int) * 2 * NN, 256);
    int* rowptr = (int*)p;        p += align_up(sizeof(int) * (NN + 1), 256);
    int* partial = (int*)p;       p += align_up(sizeof(int) * (NBLK + 1), 256);
    int* csr = (int*)p;           p += align_up(sizeof(int) * NE, 256);

    hipMemsetAsync(deg, 0, sizeof(int) * 2 * NN, stream);

    transpose_w_k<<<(4 * HD * HD) / 256, 256, 0, stream>>>(W_in, W_layers, WT);
    count_deg_k<<<(NE + 255) / 256, 256, 0, stream>>>(dst, deg);
    scan_partial_k<<<NBLK, 1024, 0, stream>>>(deg, rowptr, partial);
    scan_partials2_k<<<1, 64, 0, stream>>>(partial);
    add_off_isq_k<<<NBLK, 1024, 0, stream>>>(deg, rowptr, partial, isq);
    csr_fill_k<<<(NE + 255) / 256, 256, 0, stream>>>(src, dst, rowptr, cursor, csr);

    int gblocks = (NN + 63) / 64; // 782
    // h = x @ W_in + b_in
    gemm_mfma_k<0><<<gblocks, 256, 0, stream>>>(x, WT, b_in, h, nullptr, NN);

    for (int l = 0; l < NL; ++l) {
        // mh = bf16((h @ W_l) * isq[row])
        gemm_mfma_k<1><<<gblocks, 256, 0, stream>>>(h, WT + (size_t)(l + 1) * HD * HD,
                                                    isq, nullptr, mh, NN);
        // h = gelu(isq*(sum mh[src] + mh[v]) + b_l) + h
        aggregate_k<<<(NN + 3) / 4, 256, 0, stream>>>(mh, rowptr, csr, isq,
                                                      b_layers + (size_t)l * HD, h);
    }
}

// Round 4
// 267.758 us; speedup vs baseline: 1.4971x; 1.0902x over previous
//
#include <hip/hip_runtime.h>
#include <hip/hip_bf16.h>
#include <math.h>

#define NN 50000
#define NE 600000
#define HD 128
#define NL 3
#define NBLK 49   // ceil(NN/1024)

typedef __attribute__((ext_vector_type(8))) short short8;
typedef __attribute__((ext_vector_type(4))) float f32x4;

__device__ __forceinline__ ushort f2bf(float v) {
    union { float f; unsigned u; } c; c.f = v;
    unsigned u = c.u;
    u = (u + 0x7fffu + ((u >> 16) & 1u)) >> 16;
    return (ushort)u;
}

// ---------------- degree ----------------

__global__ void count_deg_k(const int* __restrict__ dst, int* __restrict__ deg) {
    int e = blockIdx.x * blockDim.x + threadIdx.x;
    if (e < NE) atomicAdd(&deg[dst[e]], 1);
}

// ---------------- 3-phase scan: deg -> rowptr (exclusive) ----------------

__global__ __launch_bounds__(1024) void scan_partial_k(const int* __restrict__ deg,
                                                       int* __restrict__ rowptr,
                                                       int* __restrict__ partial) {
    __shared__ int wsum[16];
    int tid = threadIdx.x;
    int lane = tid & 63, w = tid >> 6;
    int v = blockIdx.x * 1024 + tid;
    int x = (v < NN) ? deg[v] : 0;
    int s = x;
    #pragma unroll
    for (int off = 1; off < 64; off <<= 1) {
        int t = __shfl_up(s, off);
        if (lane >= off) s += t;
    }
    if (lane == 63) wsum[w] = s;
    __syncthreads();
    if (w == 0) {
        int t = (lane < 16) ? wsum[lane] : 0;
        #pragma unroll
        for (int off = 1; off < 16; off <<= 1) {
            int u = __shfl_up(t, off);
            if (lane >= off) t += u;
        }
        if (lane < 16) wsum[lane] = t;
    }
    __syncthreads();
    int incl = s + ((w > 0) ? wsum[w - 1] : 0);
    if (v < NN) rowptr[v] = incl - x;
    if (tid == 1023) partial[blockIdx.x] = incl;
}

__global__ void scan_partials2_k(int* __restrict__ partial) {
    int lane = threadIdx.x & 63;
    int x = (lane < NBLK) ? partial[lane] : 0;
    int s = x;
    #pragma unroll
    for (int off = 1; off < 64; off <<= 1) {
        int t = __shfl_up(s, off);
        if (lane >= off) s += t;
    }
    if (lane < NBLK) partial[lane] = s - x;
    if (lane == NBLK - 1) partial[NBLK] = s;
}

__global__ __launch_bounds__(1024) void add_off_isq_k(const int* __restrict__ deg,
                                                      int* __restrict__ rowptr,
                                                      const int* __restrict__ partial,
                                                      float* __restrict__ isq) {
    int v = blockIdx.x * 1024 + threadIdx.x;
    if (v < NN) {
        rowptr[v] += partial[blockIdx.x];
        isq[v] = rsqrtf((float)(deg[v] + 1));
    }
    if (v == 0) rowptr[NN] = partial[NBLK];
}

// csr stores BYTE offsets (src*256) to kill per-edge address arithmetic
__global__ void csr_fill_k(const int* __restrict__ src, const int* __restrict__ dst,
                           const int* __restrict__ rowptr, int* __restrict__ cursor,
                           int* __restrict__ csrb) {
    int e = blockIdx.x * blockDim.x + threadIdx.x;
    if (e < NE) {
        int d = dst[e];
        int pos = atomicAdd(&cursor[d], 1);
        csrb[rowptr[d] + pos] = src[e] << 8; // row byte offset (HD*2 = 256 B)
    }
}

// ---------------- weight transpose+convert: WT[m][c][k] = bf16(W_m[k][c]) ----
__global__ void transpose_w_k(const float* __restrict__ W_in,
                              const float* __restrict__ W_layers,
                              ushort* __restrict__ WT) {
    int idx = blockIdx.x * blockDim.x + threadIdx.x;
    int m = idx >> 14;
    int c = (idx >> 7) & 127;
    int k = idx & 127;
    const float* W = (m == 0) ? W_in : (W_layers + (size_t)(m - 1) * HD * HD);
    WT[idx] = f2bf(W[k * HD + c]);
}

// ---------------- MFMA GEMM: out = A[nrows,128] @ W[128,128] -----------------
// MODE 0: A f32 (x).  h[r][c] = acc + bias[c];  hb = bf16(h)
// MODE 1: A bf16 (hb). mh[r][c] = bf16(acc * isq[r])
template<int MODE>
__global__ __launch_bounds__(256) void gemm_mfma_k(const void* __restrict__ Av,
                                                   const ushort* __restrict__ WT,
                                                   const float* __restrict__ bs,
                                                   float* __restrict__ out_f32,
                                                   ushort* __restrict__ out_b16,
                                                   int nrows) {
    __shared__ ushort swT[HD * HD]; // 32 KB, XOR-swizzled [col][k]
    int tid = threadIdx.x;
    #pragma unroll
    for (int i = 0; i < 8; ++i) {
        int chunk = tid + i * 256;
        int lin = chunk << 4;
        int n = lin >> 8;
        int swz = lin ^ ((n & 7) << 4);
        *(float4*)((char*)swT + swz) = *(const float4*)(WT + chunk * 8);
    }
    __syncthreads();

    int w = tid >> 6, l = tid & 63;
    int ar = l & 15, ag = l >> 4;
    int r0 = blockIdx.x * 64 + w * 16;
    int arow = r0 + ar;
    bool arow_ok = arow < nrows;

    short8 afr[4];
    #pragma unroll
    for (int ks = 0; ks < 4; ++ks) {
        if (MODE == 0) {
            short8 fr = {0,0,0,0,0,0,0,0};
            if (arow_ok) {
                const float* Af = (const float*)Av;
                float4 p0 = *(const float4*)(Af + (size_t)arow * HD + ks * 32 + ag * 8);
                float4 p1 = *(const float4*)(Af + (size_t)arow * HD + ks * 32 + ag * 8 + 4);
                fr[0] = (short)f2bf(p0.x); fr[1] = (short)f2bf(p0.y);
                fr[2] = (short)f2bf(p0.z); fr[3] = (short)f2bf(p0.w);
                fr[4] = (short)f2bf(p1.x); fr[5] = (short)f2bf(p1.y);
                fr[6] = (short)f2bf(p1.z); fr[7] = (short)f2bf(p1.w);
            }
            afr[ks] = fr;
        } else {
            const ushort* Ab = (const ushort*)Av;
            afr[ks] = arow_ok ? *(const short8*)(Ab + (size_t)arow * HD + ks * 32 + ag * 8)
                              : short8{0,0,0,0,0,0,0,0};
        }
    }

    f32x4 acc[8];
    #pragma unroll
    for (int t = 0; t < 8; ++t) acc[t] = f32x4{0.f, 0.f, 0.f, 0.f};

    #pragma unroll
    for (int ks = 0; ks < 4; ++ks) {
        #pragma unroll
        for (int t = 0; t < 8; ++t) {
            int n = t * 16 + ar;
            int lin = (n << 8) + ks * 64 + ag * 16;
            int swz = lin ^ ((ar & 7) << 4);
            short8 b = *(const short8*)((const char*)swT + swz);
            acc[t] = __builtin_amdgcn_mfma_f32_16x16x32_bf16(afr[ks], b, acc[t], 0, 0, 0);
        }
    }

    #pragma unroll
    for (int q = 0; q < 4; ++q) {
        int row = r0 + ag * 4 + q;
        if (row >= nrows) continue;
        if (MODE == 0) {
            #pragma unroll
            for (int t = 0; t < 8; ++t) {
                int col = t * 16 + ar;
                float v = acc[t][q] + bs[col];
                out_f32[(size_t)row * HD + col] = v;
                out_b16[(size_t)row * HD + col] = f2bf(v);
            }
        } else {
            float s = bs[row];
            #pragma unroll
            for (int t = 0; t < 8; ++t) {
                int col = t * 16 + ar;
                out_b16[(size_t)row * HD + col] = f2bf(acc[t][q] * s);
            }
        }
    }
}

// ---------------- aggregation: one wave per node, lean serial loop -----------
// h[v] = gelu( isq[v]*(sum_in mh[src] + mh[v]) + b ) + h[v];  hb = bf16(h)
template<int WRITE_HB>
__global__ __launch_bounds__(256) void aggregate_k(const ushort* __restrict__ mh,
                                                   const int* __restrict__ rowptr,
                                                   const int* __restrict__ csrb,
                                                   const float* __restrict__ isq,
                                                   const float* __restrict__ bias,
                                                   float* __restrict__ h,
                                                   ushort* __restrict__ hb) {
    int gw = (int)((blockIdx.x * blockDim.x + threadIdx.x) >> 6);
    int lane = threadIdx.x & 63;
    if (gw >= NN) return;
    int v = gw;
    int2 rp = *(const int2*)&rowptr[v];
    const char* mh_lane = (const char*)mh + lane * 4; // this lane's 2 channels

    // self-loop init
    uint sp = *(const uint*)(mh_lane + ((size_t)v << 8));
    union { uint u; float f; } c0, c1;
    c0.u = sp << 16; c1.u = sp & 0xffff0000u;
    float accx = c0.f, accy = c1.f;

    for (int i = rp.x; i < rp.y; i += 64) {
        int cnt = min(64, rp.y - i);
        int offs = (i + lane < rp.y) ? csrb[i + lane] : 0;
        for (int j = 0; j < cnt; ++j) {
            int o = __shfl(offs, j);
            uint p = *(const uint*)(mh_lane + o);
            union { uint u; float f; } lo, hi;
            lo.u = p << 16; hi.u = p & 0xffff0000u;
            accx += lo.f; accy += hi.f;
        }
    }

    float is = isq[v];
    float2 b = *(const float2*)&bias[lane * 2];
    float ax = accx * is + b.x;
    float ay = accy * is + b.y;
    float gx = 0.5f * ax * (1.f + erff(ax * 0.70710678118654752f));
    float gy = 0.5f * ay * (1.f + erff(ay * 0.70710678118654752f));
    float* hp = h + (size_t)v * HD + lane * 2;
    float2 hv = *(const float2*)hp;
    hv.x += gx; hv.y += gy;
    *(float2*)hp = hv;
    if (WRITE_HB) {
        uint packed = ((uint)f2bf(hv.x)) | (((uint)f2bf(hv.y)) << 16);
        *(uint*)((char*)hb + ((size_t)v << 8) + lane * 4) = packed;
    }
}

// ---------------- launch ----------------

static inline size_t align_up(size_t x, size_t a) { return (x + a - 1) & ~(a - 1); }

extern "C" void kernel_launch(void* const* d_in, const int* in_sizes, int n_in,
                              void* d_out, int out_size, void* d_ws, size_t ws_size,
                              hipStream_t stream) {
    const float* x        = (const float*)d_in[0];
    const int*   eidx     = (const int*)d_in[1];
    const float* W_in     = (const float*)d_in[2];
    const float* b_in     = (const float*)d_in[3];
    const float* W_layers = (const float*)d_in[4];
    const float* b_layers = (const float*)d_in[5];
    float* h = (float*)d_out;

    const int* src = eidx;
    const int* dst = eidx + NE;

    // workspace carve-up (~33 MB)
    char* p = (char*)d_ws;
    ushort* mh = (ushort*)p;      p += align_up(sizeof(ushort) * (size_t)NN * HD, 256);
    ushort* hb = (ushort*)p;      p += align_up(sizeof(ushort) * (size_t)NN * HD, 256);
    ushort* WT = (ushort*)p;      p += align_up(sizeof(ushort) * 4 * HD * HD, 256);
    float* isq = (float*)p;       p += align_up(sizeof(float) * NN, 256);
    int* deg = (int*)p;           // deg and cursor adjacent -> one memset
    int* cursor = deg + NN;       p += align_up(sizeof(int) * 2 * NN, 256);
    int* rowptr = (int*)p;        p += align_up(sizeof(int) * (NN + 1), 256);
    int* partial = (int*)p;       p += align_up(sizeof(int) * (NBLK + 1), 256);
    int* csrb = (int*)p;          p += align_up(sizeof(int) * NE, 256);

    hipMemsetAsync(deg, 0, sizeof(int) * 2 * NN, stream);

    transpose_w_k<<<(4 * HD * HD) / 256, 256, 0, stream>>>(W_in, W_layers, WT);
    count_deg_k<<<(NE + 255) / 256, 256, 0, stream>>>(dst, deg);
    scan_partial_k<<<NBLK, 1024, 0, stream>>>(deg, rowptr, partial);
    scan_partials2_k<<<1, 64, 0, stream>>>(partial);
    add_off_isq_k<<<NBLK, 1024, 0, stream>>>(deg, rowptr, partial, isq);
    csr_fill_k<<<(NE + 255) / 256, 256, 0, stream>>>(src, dst, rowptr, cursor, csrb);

    int gblocks = (NN + 63) / 64; // 782
    // h = x @ W_in + b_in ; hb = bf16(h)
    gemm_mfma_k<0><<<gblocks, 256, 0, stream>>>(x, WT, b_in, h, hb, NN);

    for (int l = 0; l < NL; ++l) {
        // mh = bf16((hb @ W_l) * isq[row])
        gemm_mfma_k<1><<<gblocks, 256, 0, stream>>>(hb, WT + (size_t)(l + 1) * HD * HD,
                                                    isq, nullptr, mh, NN);
        // h = gelu(isq*(sum mh[src] + mh[v]) + b_l) + h ; hb = bf16(h) except last
        if (l < NL - 1)
            aggregate_k<1><<<(NN + 3) / 4, 256, 0, stream>>>(mh, rowptr, csrb, isq,
                                                             b_layers + (size_t)l * HD, h, hb);
        else
            aggregate_k<0><<<(NN + 3) / 4, 256, 0, stream>>>(mh, rowptr, csrb, isq,
                                                             b_layers + (size_t)l * HD, h, hb);
    }
}

// Round 5
// 223.965 us; speedup vs baseline: 1.7899x; 1.1955x over previous
//
#include <hip/hip_runtime.h>
#include <hip/hip_bf16.h>
#include <math.h>

#define NN 50000
#define NE 600000
#define HD 128
#define NL 3
#define NBLK 49   // ceil(NN/1024)

typedef __attribute__((ext_vector_type(8))) short short8;
typedef __attribute__((ext_vector_type(4))) float f32x4;

__device__ __forceinline__ ushort f2bf(float v) {
    union { float f; unsigned u; } c; c.f = v;
    unsigned u = c.u;
    u = (u + 0x7fffu + ((u >> 16) & 1u)) >> 16;
    return (ushort)u;
}
__device__ __forceinline__ float u2f(uint u) {
    union { uint u; float f; } c; c.u = u; return c.f;
}

// ---------------- degree ----------------

__global__ void count_deg_k(const int* __restrict__ dst, int* __restrict__ deg) {
    int e = blockIdx.x * blockDim.x + threadIdx.x;
    if (e < NE) atomicAdd(&deg[dst[e]], 1);
}

// ---------------- 3-phase scan: deg -> rowptr (exclusive) ----------------

__global__ __launch_bounds__(1024) void scan_partial_k(const int* __restrict__ deg,
                                                       int* __restrict__ rowptr,
                                                       int* __restrict__ partial) {
    __shared__ int wsum[16];
    int tid = threadIdx.x;
    int lane = tid & 63, w = tid >> 6;
    int v = blockIdx.x * 1024 + tid;
    int x = (v < NN) ? deg[v] : 0;
    int s = x;
    #pragma unroll
    for (int off = 1; off < 64; off <<= 1) {
        int t = __shfl_up(s, off);
        if (lane >= off) s += t;
    }
    if (lane == 63) wsum[w] = s;
    __syncthreads();
    if (w == 0) {
        int t = (lane < 16) ? wsum[lane] : 0;
        #pragma unroll
        for (int off = 1; off < 16; off <<= 1) {
            int u = __shfl_up(t, off);
            if (lane >= off) t += u;
        }
        if (lane < 16) wsum[lane] = t;
    }
    __syncthreads();
    int incl = s + ((w > 0) ? wsum[w - 1] : 0);
    if (v < NN) rowptr[v] = incl - x;
    if (tid == 1023) partial[blockIdx.x] = incl;
}

__global__ void scan_partials2_k(int* __restrict__ partial) {
    int lane = threadIdx.x & 63;
    int x = (lane < NBLK) ? partial[lane] : 0;
    int s = x;
    #pragma unroll
    for (int off = 1; off < 64; off <<= 1) {
        int t = __shfl_up(s, off);
        if (lane >= off) s += t;
    }
    if (lane < NBLK) partial[lane] = s - x;
    if (lane == NBLK - 1) partial[NBLK] = s;
}

__global__ __launch_bounds__(1024) void add_off_isq_k(const int* __restrict__ deg,
                                                      int* __restrict__ rowptr,
                                                      const int* __restrict__ partial,
                                                      float* __restrict__ isq) {
    int v = blockIdx.x * 1024 + threadIdx.x;
    if (v < NN) {
        rowptr[v] += partial[blockIdx.x];
        isq[v] = rsqrtf((float)(deg[v] + 1));
    }
    if (v == 0) rowptr[NN] = partial[NBLK];
}

// csr stores BYTE offsets (src*256)
__global__ void csr_fill_k(const int* __restrict__ src, const int* __restrict__ dst,
                           const int* __restrict__ rowptr, int* __restrict__ cursor,
                           int* __restrict__ csrb) {
    int e = blockIdx.x * blockDim.x + threadIdx.x;
    if (e < NE) {
        int d = dst[e];
        int pos = atomicAdd(&cursor[d], 1);
        csrb[rowptr[d] + pos] = src[e] << 8;
    }
}

// ---------------- weight transpose+convert: WT[m][c][k] = bf16(W_m[k][c]) ----
__global__ void transpose_w_k(const float* __restrict__ W_in,
                              const float* __restrict__ W_layers,
                              ushort* __restrict__ WT) {
    int idx = blockIdx.x * blockDim.x + threadIdx.x;
    int m = idx >> 14;
    int c = (idx >> 7) & 127;
    int k = idx & 127;
    const float* W = (m == 0) ? W_in : (W_layers + (size_t)(m - 1) * HD * HD);
    WT[idx] = f2bf(W[k * HD + c]);
}

// ---------------- MFMA GEMM: out = A[nrows,128] @ W[128,128] -----------------
// MODE 0: A f32 (x).  h[r][c] = acc + bias[c];  hb = bf16(h)
// MODE 1: A bf16 (hb). mh[r][c] = bf16(acc * isq[r])
template<int MODE>
__global__ __launch_bounds__(256) void gemm_mfma_k(const void* __restrict__ Av,
                                                   const ushort* __restrict__ WT,
                                                   const float* __restrict__ bs,
                                                   float* __restrict__ out_f32,
                                                   ushort* __restrict__ out_b16,
                                                   int nrows) {
    __shared__ ushort swT[HD * HD]; // 32 KB, XOR-swizzled [col][k]
    int tid = threadIdx.x;
    #pragma unroll
    for (int i = 0; i < 8; ++i) {
        int chunk = tid + i * 256;
        int lin = chunk << 4;
        int n = lin >> 8;
        int swz = lin ^ ((n & 7) << 4);
        *(float4*)((char*)swT + swz) = *(const float4*)(WT + chunk * 8);
    }
    __syncthreads();

    int w = tid >> 6, l = tid & 63;
    int ar = l & 15, ag = l >> 4;
    int r0 = blockIdx.x * 64 + w * 16;
    int arow = r0 + ar;
    bool arow_ok = arow < nrows;

    short8 afr[4];
    #pragma unroll
    for (int ks = 0; ks < 4; ++ks) {
        if (MODE == 0) {
            short8 fr = {0,0,0,0,0,0,0,0};
            if (arow_ok) {
                const float* Af = (const float*)Av;
                float4 p0 = *(const float4*)(Af + (size_t)arow * HD + ks * 32 + ag * 8);
                float4 p1 = *(const float4*)(Af + (size_t)arow * HD + ks * 32 + ag * 8 + 4);
                fr[0] = (short)f2bf(p0.x); fr[1] = (short)f2bf(p0.y);
                fr[2] = (short)f2bf(p0.z); fr[3] = (short)f2bf(p0.w);
                fr[4] = (short)f2bf(p1.x); fr[5] = (short)f2bf(p1.y);
                fr[6] = (short)f2bf(p1.z); fr[7] = (short)f2bf(p1.w);
            }
            afr[ks] = fr;
        } else {
            const ushort* Ab = (const ushort*)Av;
            afr[ks] = arow_ok ? *(const short8*)(Ab + (size_t)arow * HD + ks * 32 + ag * 8)
                              : short8{0,0,0,0,0,0,0,0};
        }
    }

    f32x4 acc[8];
    #pragma unroll
    for (int t = 0; t < 8; ++t) acc[t] = f32x4{0.f, 0.f, 0.f, 0.f};

    #pragma unroll
    for (int ks = 0; ks < 4; ++ks) {
        #pragma unroll
        for (int t = 0; t < 8; ++t) {
            int n = t * 16 + ar;
            int lin = (n << 8) + ks * 64 + ag * 16;
            int swz = lin ^ ((ar & 7) << 4);
            short8 b = *(const short8*)((const char*)swT + swz);
            acc[t] = __builtin_amdgcn_mfma_f32_16x16x32_bf16(afr[ks], b, acc[t], 0, 0, 0);
        }
    }

    #pragma unroll
    for (int q = 0; q < 4; ++q) {
        int row = r0 + ag * 4 + q;
        if (row >= nrows) continue;
        if (MODE == 0) {
            #pragma unroll
            for (int t = 0; t < 8; ++t) {
                int col = t * 16 + ar;
                float v = acc[t][q] + bs[col];
                out_f32[(size_t)row * HD + col] = v;
                out_b16[(size_t)row * HD + col] = f2bf(v);
            }
        } else {
            float s = bs[row];
            #pragma unroll
            for (int t = 0; t < 8; ++t) {
                int col = t * 16 + ar;
                out_b16[(size_t)row * HD + col] = f2bf(acc[t][q] * s);
            }
        }
    }
}

// ---------------- aggregation: one wave per node, MLP-4 clean unroll ---------
// h[v] = gelu( isq[v]*(sum_in mh[src] + mh[v]) + b ) + h[v];  hb = bf16(h)
template<int WRITE_HB>
__global__ __launch_bounds__(256) void aggregate_k(const ushort* __restrict__ mh,
                                                   const int* __restrict__ rowptr,
                                                   const int* __restrict__ csrb,
                                                   const float* __restrict__ isq,
                                                   const float* __restrict__ bias,
                                                   float* __restrict__ h,
                                                   ushort* __restrict__ hb) {
    int gw = (int)((blockIdx.x * blockDim.x + threadIdx.x) >> 6);
    int lane = threadIdx.x & 63;
    if (gw >= NN) return;
    int v = gw;
    int2 rp = *(const int2*)&rowptr[v];
    const char* mh_lane = (const char*)mh + lane * 4; // this lane's 2 channels

    // self-loop init
    uint sp = *(const uint*)(mh_lane + ((size_t)v << 8));
    float accx = u2f(sp << 16), accy = u2f(sp & 0xffff0000u);

    for (int i = rp.x; i < rp.y; i += 64) {
        int cnt = min(64, rp.y - i);
        int offs = (i + lane < rp.y) ? csrb[i + lane] : 0;
        int j = 0;
        // 4-wide branch-free body: 4 independent gathers in flight
        for (; j + 4 <= cnt; j += 4) {
            int o0 = __shfl(offs, j);
            int o1 = __shfl(offs, j + 1);
            int o2 = __shfl(offs, j + 2);
            int o3 = __shfl(offs, j + 3);
            uint p0 = *(const uint*)(mh_lane + o0);
            uint p1 = *(const uint*)(mh_lane + o1);
            uint p2 = *(const uint*)(mh_lane + o2);
            uint p3 = *(const uint*)(mh_lane + o3);
            accx += u2f(p0 << 16); accy += u2f(p0 & 0xffff0000u);
            accx += u2f(p1 << 16); accy += u2f(p1 & 0xffff0000u);
            accx += u2f(p2 << 16); accy += u2f(p2 & 0xffff0000u);
            accx += u2f(p3 << 16); accy += u2f(p3 & 0xffff0000u);
        }
        for (; j < cnt; ++j) {
            int o = __shfl(offs, j);
            uint p = *(const uint*)(mh_lane + o);
            accx += u2f(p << 16); accy += u2f(p & 0xffff0000u);
        }
    }

    float is = isq[v];
    float2 b = *(const float2*)&bias[lane * 2];
    float ax = accx * is + b.x;
    float ay = accy * is + b.y;
    float gx = 0.5f * ax * (1.f + erff(ax * 0.70710678118654752f));
    float gy = 0.5f * ay * (1.f + erff(ay * 0.70710678118654752f));
    float* hp = h + (size_t)v * HD + lane * 2;
    float2 hv = *(const float2*)hp;
    hv.x += gx; hv.y += gy;
    *(float2*)hp = hv;
    if (WRITE_HB) {
        uint packed = ((uint)f2bf(hv.x)) | (((uint)f2bf(hv.y)) << 16);
        *(uint*)((char*)hb + ((size_t)v << 8) + lane * 4) = packed;
    }
}

// ---------------- launch ----------------

static inline size_t align_up(size_t x, size_t a) { return (x + a - 1) & ~(a - 1); }

extern "C" void kernel_launch(void* const* d_in, const int* in_sizes, int n_in,
                              void* d_out, int out_size, void* d_ws, size_t ws_size,
                              hipStream_t stream) {
    const float* x        = (const float*)d_in[0];
    const int*   eidx     = (const int*)d_in[1];
    const float* W_in     = (const float*)d_in[2];
    const float* b_in     = (const float*)d_in[3];
    const float* W_layers = (const float*)d_in[4];
    const float* b_layers = (const float*)d_in[5];
    float* h = (float*)d_out;

    const int* src = eidx;
    const int* dst = eidx + NE;

    // workspace carve-up (~33 MB)
    char* p = (char*)d_ws;
    ushort* mh = (ushort*)p;      p += align_up(sizeof(ushort) * (size_t)NN * HD, 256);
    ushort* hb = (ushort*)p;      p += align_up(sizeof(ushort) * (size_t)NN * HD, 256);
    ushort* WT = (ushort*)p;      p += align_up(sizeof(ushort) * 4 * HD * HD, 256);
    float* isq = (float*)p;       p += align_up(sizeof(float) * NN, 256);
    int* deg = (int*)p;           // deg and cursor adjacent -> one memset
    int* cursor = deg + NN;       p += align_up(sizeof(int) * 2 * NN, 256);
    int* rowptr = (int*)p;        p += align_up(sizeof(int) * (NN + 1), 256);
    int* partial = (int*)p;       p += align_up(sizeof(int) * (NBLK + 1), 256);
    int* csrb = (int*)p;          p += align_up(sizeof(int) * NE, 256);

    hipMemsetAsync(deg, 0, sizeof(int) * 2 * NN, stream);

    transpose_w_k<<<(4 * HD * HD) / 256, 256, 0, stream>>>(W_in, W_layers, WT);
    count_deg_k<<<(NE + 255) / 256, 256, 0, stream>>>(dst, deg);
    scan_partial_k<<<NBLK, 1024, 0, stream>>>(deg, rowptr, partial);
    scan_partials2_k<<<1, 64, 0, stream>>>(partial);
    add_off_isq_k<<<NBLK, 1024, 0, stream>>>(deg, rowptr, partial, isq);
    csr_fill_k<<<(NE + 255) / 256, 256, 0, stream>>>(src, dst, rowptr, cursor, csrb);

    int gblocks = (NN + 63) / 64; // 782
    // h = x @ W_in + b_in ; hb = bf16(h)
    gemm_mfma_k<0><<<gblocks, 256, 0, stream>>>(x, WT, b_in, h, hb, NN);

    for (int l = 0; l < NL; ++l) {
        // mh = bf16((hb @ W_l) * isq[row])
        gemm_mfma_k<1><<<gblocks, 256, 0, stream>>>(hb, WT + (size_t)(l + 1) * HD * HD,
                                                    isq, nullptr, mh, NN);
        // h = gelu(isq*(sum mh[src] + mh[v]) + b_l) + h ; hb = bf16(h) except last
        if (l < NL - 1)
            aggregate_k<1><<<(NN + 3) / 4, 256, 0, stream>>>(mh, rowptr, csrb, isq,
                                                             b_layers + (size_t)l * HD, h, hb);
        else
            aggregate_k<0><<<(NN + 3) / 4, 256, 0, stream>>>(mh, rowptr, csrb, isq,
                                                             b_layers + (size_t)l * HD, h, hb);
    }
}